// Round 13
// baseline (352.407 us; speedup 1.0000x reference)
//
#include <hip/hip_runtime.h>

// ---------------------------------------------------------------------------
// 12-qubit state-vector sim, one sample per 64-lane wave, 4 samples/block.
// Storage index p (12 bits): bits 0..5 = per-thread local index j,
// bits 6..11 = lane id. Logical k = M*p over GF(2); CNOTs folded into M at
// compile time; each Rot gate = pair-mask (col of M^-1) + side-mask (row M).
// Wire w <-> bit (11-w) of k (PennyLane big-endian).
//
// Packed layout (R11): vector t = j>>1 holds halves h=0,1. rr[t]={re0,re1},
// ii[t]={im0,im1}; complex update = pure packed FMAs, side-bit variants in
// compile-time coefficient vectors. Pipe split (R7/R12): cost<=2 -> all-DPP.
//
// Round-13 change: HYBRID WITHIN expensive gates (cost>2, formerly all-DS).
// R12 counters: 26% true stall cycles (wall 845k vs VALU-busy 625k /SIMD),
// DS pipe only ~58% busy -> latency-limited at per-gate lgkmcnt waits with
// only 2 waves/SIMD. Fix: per 8-t chunk, issue a 4-t DS bpermute batch,
// then compute 4 t's via the full DPP chain (independent VALU work covering
// the DS latency), then consume the DS batch. DS words/wave halve; the DS
// wait overlaps same-wave VALU instead of requiring a second wave.
// ---------------------------------------------------------------------------

#define N_GATES 48

typedef float v2f __attribute__((ext_vector_type(2)));

#if __has_builtin(__builtin_amdgcn_permlane16_swap) && __has_builtin(__builtin_amdgcn_permlane32_swap)
#define HAS_PLSWAP 1
#else
#define HAS_PLSWAP 0
#endif

struct Circ {
    unsigned pair[N_GATES];
    unsigned side[N_GATES];
    unsigned meas[12];
};

constexpr Circ make_circ() {
    Circ c{};
    unsigned Mrow[12] = {}, Ucol[12] = {};   // M rows, M^-1 columns
    for (int i = 0; i < 12; ++i) { Mrow[i] = 1u << i; Ucol[i] = 1u << i; }
    int g = 0;
    for (int l = 0; l < 4; ++l) {
        for (int w = 0; w < 12; ++w) {
            int b = 11 - w;
            c.pair[g] = Ucol[b];
            c.side[g] = Mrow[b];
            ++g;
        }
        for (int i = 0; i < 11; ++i) {       // CNOT chain (i -> i+1)
            int cb = 11 - i, tb = 10 - i;
            Mrow[tb] ^= Mrow[cb];
            Ucol[cb] ^= Ucol[tb];
        }
        Mrow[11] ^= Mrow[0];                 // CNOT(11 -> 0)
        Ucol[0]  ^= Ucol[11];
    }
    for (int w = 0; w < 12; ++w) c.meas[w] = Mrow[11 - w];
    return c;
}

constexpr Circ CIRC = make_circ();

__device__ __forceinline__ constexpr int pidx(int c, int msb) {
    return ((c & ~(msb - 1)) << 1) | (c & (msb - 1));
}

constexpr int dpp_cost(unsigned pmh) {
    constexpr int low[16] = {0,1,1,1,2,2,2,1,2,3,3,3,2,2,2,1};
    int c = low[pmh & 15u];
    if (pmh & 16u) c += 2;
    if (pmh & 32u) c += 2;
    return c;
}

// ---- VALU-pipe lane-xor primitives --------------------------------------
__device__ __forceinline__ int dpp1(int w){ return __builtin_amdgcn_mov_dpp(w, 0xB1,  0xF, 0xF, true); }
__device__ __forceinline__ int dpp2(int w){ return __builtin_amdgcn_mov_dpp(w, 0x4E,  0xF, 0xF, true); }
__device__ __forceinline__ int dpp3(int w){ return __builtin_amdgcn_mov_dpp(w, 0x1B,  0xF, 0xF, true); }
__device__ __forceinline__ int dpp7(int w){ return __builtin_amdgcn_mov_dpp(w, 0x141, 0xF, 0xF, true); }
__device__ __forceinline__ int dppF(int w){ return __builtin_amdgcn_mov_dpp(w, 0x140, 0xF, 0xF, true); }

template <unsigned V>
__device__ __forceinline__ int dpp_low(int w) {
    if constexpr (V == 0)  return w;
    else if constexpr (V == 1)  return dpp1(w);
    else if constexpr (V == 2)  return dpp2(w);
    else if constexpr (V == 3)  return dpp3(w);
    else if constexpr (V == 7)  return dpp7(w);
    else if constexpr (V == 15) return dppF(w);
    else if constexpr (V == 4)  return dpp3(dpp7(w));
    else if constexpr (V == 5)  return dpp2(dpp7(w));
    else if constexpr (V == 6)  return dpp1(dpp7(w));
    else if constexpr (V == 8)  return dpp7(dppF(w));
    else if constexpr (V == 12) return dpp3(dppF(w));
    else if constexpr (V == 13) return dpp2(dppF(w));
    else if constexpr (V == 14) return dpp1(dppF(w));
    else if constexpr (V == 9)  return dpp1(dpp7(dppF(w)));
    else if constexpr (V == 10) return dpp2(dpp7(dppF(w)));
    else return dpp3(dpp7(dppF(w)));   // V == 11
}

template <unsigned PMH>
__device__ __forceinline__ unsigned xword(unsigned w, bool l16, bool l32) {
    unsigned t = (unsigned)dpp_low<PMH & 15u>((int)w);
#if HAS_PLSWAP
    if constexpr ((PMH & 16u) != 0) {
        auto r = __builtin_amdgcn_permlane16_swap(t, t, false, false);
        t = l16 ? r[0] : r[1];
    }
    if constexpr ((PMH & 32u) != 0) {
        auto r = __builtin_amdgcn_permlane32_swap(t, t, false, false);
        t = l32 ? r[0] : r[1];
    }
#else
    if constexpr ((PMH & 48u) != 0)
        t = (unsigned)__shfl_xor((int)t, (int)(PMH & 48u), 64);
#endif
    return t;
}

template <unsigned PMH>
__device__ __forceinline__ v2f xpartner(v2f v, bool l16, bool l32) {
    union { v2f f; unsigned u[2]; } a;
    a.f = v;
    a.u[0] = xword<PMH>(a.u[0], l16, l32);
    a.u[1] = xword<PMH>(a.u[1], l16, l32);
    return a.f;
}

// DS exchange with hoisted byte address (addr = (lane^pmh)<<2)
__device__ __forceinline__ v2f dsx(int addr, v2f v) {
    union { v2f f; int u[2]; } a;
    a.f = v;
    a.u[0] = __builtin_amdgcn_ds_bpermute(addr, a.u[0]);
    a.u[1] = __builtin_amdgcn_ds_bpermute(addr, a.u[1]);
    return a.f;
}

// out = c1*x1 + c2*x2 + c3*x3 + c4*x4 (packed, no swizzles)
__device__ __forceinline__ v2f fmad4(v2f c1, v2f x1, v2f c2, v2f x2,
                                     v2f c3, v2f x3, v2f c4, v2f x4) {
    return __builtin_elementwise_fma(c1, x1,
           __builtin_elementwise_fma(c2, x2,
           __builtin_elementwise_fma(c3, x3, c4 * x4)));
}

template <int G>
__device__ __forceinline__ void apply_gate(v2f (&rr)[32], v2f (&ii)[32],
                                           const float* __restrict__ m,
                                           int lane, bool l16, bool l32) {
    constexpr unsigned pm  = CIRC.pair[G];
    constexpr unsigned sm  = CIRC.side[G];
    constexpr unsigned pml = pm & 63u,  pmh = pm >> 6;
    constexpr unsigned sml = sm & 63u,  smh = sm >> 6;
    constexpr unsigned smlv = sml >> 1, pmlv = pml >> 1;
    constexpr bool smlodd = (sml & 1u) != 0;
    constexpr bool pmlodd = (pml & 1u) != 0;
    constexpr bool use_dpp = (pmh != 0u) && (dpp_cost(pmh) <= 2);   // R7 calibration

    const float u00r = m[0], u00i = m[1], u01r = m[2], u01i = m[3];
    const float u10r = m[4], u10i = m[5], u11r = m[6], u11i = m[7];
    const int sL = __popc(lane & (int)smh) & 1;
    // coef(s): own P(s)=s?u11:u00, partner Q(s)=s?u10:u01; a: s=sL, b: s=!sL
    const float par = sL ? u11r : u00r, pai = sL ? u11i : u00i;
    const float pbr = sL ? u00r : u11r, pbi = sL ? u00i : u11i;
    const float qar = sL ? u10r : u01r, qai = sL ? u10i : u01i;
    const float qbr = sL ? u01r : u10r, qbi = sL ? u01i : u10i;
    // element j=2t+h: s = sL ^ parity(t&smlv) ^ (h&smlodd).
    // variant c0 = parity(t&smlv): coef v2f halves = (s(h0), s(h1)).
    v2f PR0, PI0, PN0, QR0, QI0, QN0, PR1, PI1, PN1, QR1, QI1, QN1;
    if constexpr (!smlodd) {
        PR0 = v2f{par, par}; PI0 = v2f{pai, pai}; PN0 = v2f{-pai, -pai};
        QR0 = v2f{qar, qar}; QI0 = v2f{qai, qai}; QN0 = v2f{-qai, -qai};
        PR1 = v2f{pbr, pbr}; PI1 = v2f{pbi, pbi}; PN1 = v2f{-pbi, -pbi};
        QR1 = v2f{qbr, qbr}; QI1 = v2f{qbi, qbi}; QN1 = v2f{-qbi, -qbi};
    } else {
        PR0 = v2f{par, pbr}; PI0 = v2f{pai, pbi}; PN0 = v2f{-pai, -pbi};
        QR0 = v2f{qar, qbr}; QI0 = v2f{qai, qbi}; QN0 = v2f{-qai, -qbi};
        PR1 = v2f{pbr, par}; PI1 = v2f{pbi, pai}; PN1 = v2f{-pbi, -pai};
        QR1 = v2f{qbr, qar}; QI1 = v2f{qbi, qai}; QN1 = v2f{-qbi, -qai};
    }
#define CSEL(c, X) ((c) ? X##1 : X##0)
#define CRE(c, A, Ai, B, Bi) fmad4(CSEL(c,PR), A,  CSEL(c,PN), Ai, CSEL(c,QR), B,  CSEL(c,QN), Bi)
#define CIM(c, A, Ai, B, Bi) fmad4(CSEL(c,PR), Ai, CSEL(c,PI), A,  CSEL(c,QR), Bi, CSEL(c,QI), B)

    if constexpr (pmh == 0u && pml == 1u) {
        // partner inside the v2f: B = A.yx
#pragma unroll
        for (int t = 0; t < 32; ++t) {
            const int c0 = __builtin_parity(t & (int)smlv);
            const v2f A = rr[t], Ai = ii[t];
            const v2f B = A.yx, Bi = Ai.yx;
            rr[t] = CRE(c0, A, Ai, B, Bi);
            ii[t] = CIM(c0, A, Ai, B, Bi);
        }
    } else if constexpr (pmh == 0u && !pmlodd) {
        // in-thread vector pairs (t, t^pmlv), same half
        constexpr int msbv = 1 << (31 - __builtin_clz(pmlv));
#pragma unroll
        for (int c = 0; c < 16; ++c) {
            const int t = pidx(c, msbv), t2 = t ^ (int)pmlv;
            const int c0 = __builtin_parity(t  & (int)smlv);
            const int c1 = __builtin_parity(t2 & (int)smlv);
            const v2f A = rr[t], Ai = ii[t], B = rr[t2], Bi = ii[t2];
            rr[t]  = CRE(c0, A, Ai, B, Bi);
            ii[t]  = CIM(c0, A, Ai, B, Bi);
            rr[t2] = CRE(c1, B, Bi, A, Ai);
            ii[t2] = CIM(c1, B, Bi, A, Ai);
        }
    } else if constexpr (pmh == 0u) {
        // in-thread pairs (t, t^pmlv) with HALF SWAP (pml odd > 1)
        constexpr int msbv = 1 << (31 - __builtin_clz(pmlv));
#pragma unroll
        for (int c = 0; c < 16; ++c) {
            const int t = pidx(c, msbv), t2 = t ^ (int)pmlv;
            const int c0 = __builtin_parity(t  & (int)smlv);
            const int c1 = __builtin_parity(t2 & (int)smlv);
            const v2f A = rr[t], Ai = ii[t], B = rr[t2], Bi = ii[t2];
            const v2f BS = B.yx, BSi = Bi.yx, AS = A.yx, ASi = Ai.yx;
            rr[t]  = CRE(c0, A, Ai, BS, BSi);
            ii[t]  = CIM(c0, A, Ai, BS, BSi);
            rr[t2] = CRE(c1, B, Bi, AS, ASi);
            ii[t2] = CIM(c1, B, Bi, AS, ASi);
        }
    } else if constexpr (pml == 0u) {
        // pure cross-lane: partner = same vector, lane^pmh
        if constexpr (use_dpp) {
#pragma unroll
            for (int t = 0; t < 32; ++t) {
                const int c0 = __builtin_parity(t & (int)smlv);
                const v2f B  = xpartner<pmh>(rr[t], l16, l32);
                const v2f Bi = xpartner<pmh>(ii[t], l16, l32);
                const v2f A = rr[t], Ai = ii[t];
                rr[t] = CRE(c0, A, Ai, B, Bi);
                ii[t] = CIM(c0, A, Ai, B, Bi);
            }
        } else {
            // R13: hybrid — issue DS batch, cover with DPP half, consume DS
            const int bpa = ((lane ^ (int)pmh) << 2);
#pragma unroll
            for (int t0 = 0; t0 < 32; t0 += 8) {
                v2f B[4], Bi[4];
#pragma unroll
                for (int k = 0; k < 4; ++k) {          // issue DS: t0..t0+3
                    B[k]  = dsx(bpa, rr[t0 + k]);
                    Bi[k] = dsx(bpa, ii[t0 + k]);
                }
#pragma unroll
                for (int k = 4; k < 8; ++k) {          // DPP half: t0+4..t0+7
                    const int t = t0 + k;
                    const int c0 = __builtin_parity(t & (int)smlv);
                    const v2f Bd  = xpartner<pmh>(rr[t], l16, l32);
                    const v2f Bdi = xpartner<pmh>(ii[t], l16, l32);
                    const v2f A = rr[t], Ai = ii[t];
                    rr[t] = CRE(c0, A, Ai, Bd, Bdi);
                    ii[t] = CIM(c0, A, Ai, Bd, Bdi);
                }
#pragma unroll
                for (int k = 0; k < 4; ++k) {          // consume DS
                    const int t = t0 + k;
                    const int c0 = __builtin_parity(t & (int)smlv);
                    const v2f A = rr[t], Ai = ii[t];
                    rr[t] = CRE(c0, A, Ai, B[k], Bi[k]);
                    ii[t] = CIM(c0, A, Ai, B[k], Bi[k]);
                }
            }
        }
    } else if constexpr (pmlodd && pmlv == 0u) {
        // partner = (lane^pmh, same t, h^1): exchange + half swap
        if constexpr (use_dpp) {
#pragma unroll
            for (int t = 0; t < 32; ++t) {
                const int c0 = __builtin_parity(t & (int)smlv);
                const v2f X  = xpartner<pmh>(rr[t], l16, l32);
                const v2f Xi = xpartner<pmh>(ii[t], l16, l32);
                const v2f A = rr[t], Ai = ii[t];
                const v2f B = X.yx, Bi = Xi.yx;
                rr[t] = CRE(c0, A, Ai, B, Bi);
                ii[t] = CIM(c0, A, Ai, B, Bi);
            }
        } else {
            const int bpa = ((lane ^ (int)pmh) << 2);
#pragma unroll
            for (int t0 = 0; t0 < 32; t0 += 8) {
                v2f X[4], Xi[4];
#pragma unroll
                for (int k = 0; k < 4; ++k) {          // issue DS
                    X[k]  = dsx(bpa, rr[t0 + k]);
                    Xi[k] = dsx(bpa, ii[t0 + k]);
                }
#pragma unroll
                for (int k = 4; k < 8; ++k) {          // DPP half
                    const int t = t0 + k;
                    const int c0 = __builtin_parity(t & (int)smlv);
                    const v2f Xd  = xpartner<pmh>(rr[t], l16, l32);
                    const v2f Xdi = xpartner<pmh>(ii[t], l16, l32);
                    const v2f A = rr[t], Ai = ii[t];
                    const v2f B = Xd.yx, Bi = Xdi.yx;
                    rr[t] = CRE(c0, A, Ai, B, Bi);
                    ii[t] = CIM(c0, A, Ai, B, Bi);
                }
#pragma unroll
                for (int k = 0; k < 4; ++k) {          // consume DS
                    const int t = t0 + k;
                    const int c0 = __builtin_parity(t & (int)smlv);
                    const v2f A = rr[t], Ai = ii[t];
                    const v2f B = X[k].yx, Bi = Xi[k].yx;
                    rr[t] = CRE(c0, A, Ai, B, Bi);
                    ii[t] = CIM(c0, A, Ai, B, Bi);
                }
            }
        }
    } else if constexpr (pmlodd) {
        // pairs (t, t^pmlv) with lane exchange + half swap
        constexpr int msbv = 1 << (31 - __builtin_clz(pmlv));
        if constexpr (use_dpp) {
#pragma unroll
            for (int c = 0; c < 16; ++c) {
                const int t = pidx(c, msbv), t2 = t ^ (int)pmlv;
                const int c0 = __builtin_parity(t  & (int)smlv);
                const int c1 = __builtin_parity(t2 & (int)smlv);
                const v2f XA  = xpartner<pmh>(rr[t2], l16, l32);
                const v2f XAi = xpartner<pmh>(ii[t2], l16, l32);
                const v2f XB  = xpartner<pmh>(rr[t],  l16, l32);
                const v2f XBi = xpartner<pmh>(ii[t],  l16, l32);
                const v2f A = rr[t], Ai = ii[t], B = rr[t2], Bi = ii[t2];
                const v2f YA = XA.yx, YAi = XAi.yx, YB = XB.yx, YBi = XBi.yx;
                rr[t]  = CRE(c0, A, Ai, YA, YAi);
                ii[t]  = CIM(c0, A, Ai, YA, YAi);
                rr[t2] = CRE(c1, B, Bi, YB, YBi);
                ii[t2] = CIM(c1, B, Bi, YB, YBi);
            }
        } else {
            const int bpa = ((lane ^ (int)pmh) << 2);
#pragma unroll
            for (int cc = 0; cc < 16; cc += 4) {
                v2f XA[2], XAi[2], XB[2], XBi[2];
#pragma unroll
                for (int k = 0; k < 2; ++k) {          // issue DS: cc, cc+1
                    const int t = pidx(cc + k, msbv), t2 = t ^ (int)pmlv;
                    XA[k] = dsx(bpa, rr[t2]); XAi[k] = dsx(bpa, ii[t2]);
                    XB[k] = dsx(bpa, rr[t]);  XBi[k] = dsx(bpa, ii[t]);
                }
#pragma unroll
                for (int k = 2; k < 4; ++k) {          // DPP half: cc+2, cc+3
                    const int t = pidx(cc + k, msbv), t2 = t ^ (int)pmlv;
                    const int c0 = __builtin_parity(t  & (int)smlv);
                    const int c1 = __builtin_parity(t2 & (int)smlv);
                    const v2f DA  = xpartner<pmh>(rr[t2], l16, l32);
                    const v2f DAi = xpartner<pmh>(ii[t2], l16, l32);
                    const v2f DB  = xpartner<pmh>(rr[t],  l16, l32);
                    const v2f DBi = xpartner<pmh>(ii[t],  l16, l32);
                    const v2f A = rr[t], Ai = ii[t], B = rr[t2], Bi = ii[t2];
                    rr[t]  = CRE(c0, A, Ai, DA.yx, DAi.yx);
                    ii[t]  = CIM(c0, A, Ai, DA.yx, DAi.yx);
                    rr[t2] = CRE(c1, B, Bi, DB.yx, DBi.yx);
                    ii[t2] = CIM(c1, B, Bi, DB.yx, DBi.yx);
                }
#pragma unroll
                for (int k = 0; k < 2; ++k) {          // consume DS
                    const int t = pidx(cc + k, msbv), t2 = t ^ (int)pmlv;
                    const int c0 = __builtin_parity(t  & (int)smlv);
                    const int c1 = __builtin_parity(t2 & (int)smlv);
                    const v2f A = rr[t], Ai = ii[t], B = rr[t2], Bi = ii[t2];
                    rr[t]  = CRE(c0, A, Ai, XA[k].yx, XAi[k].yx);
                    ii[t]  = CIM(c0, A, Ai, XA[k].yx, XAi[k].yx);
                    rr[t2] = CRE(c1, B, Bi, XB[k].yx, XBi[k].yx);
                    ii[t2] = CIM(c1, B, Bi, XB[k].yx, XBi[k].yx);
                }
            }
        }
    } else {
        // mixed, pml even: pairs (t, t^pmlv) with lane exchange
        constexpr int msbv = 1 << (31 - __builtin_clz(pmlv));
        if constexpr (use_dpp) {
#pragma unroll
            for (int c = 0; c < 16; ++c) {
                const int t = pidx(c, msbv), t2 = t ^ (int)pmlv;
                const int c0 = __builtin_parity(t  & (int)smlv);
                const int c1 = __builtin_parity(t2 & (int)smlv);
                const v2f XA  = xpartner<pmh>(rr[t2], l16, l32);
                const v2f XAi = xpartner<pmh>(ii[t2], l16, l32);
                const v2f XB  = xpartner<pmh>(rr[t],  l16, l32);
                const v2f XBi = xpartner<pmh>(ii[t],  l16, l32);
                const v2f A = rr[t], Ai = ii[t], B = rr[t2], Bi = ii[t2];
                rr[t]  = CRE(c0, A, Ai, XA, XAi);
                ii[t]  = CIM(c0, A, Ai, XA, XAi);
                rr[t2] = CRE(c1, B, Bi, XB, XBi);
                ii[t2] = CIM(c1, B, Bi, XB, XBi);
            }
        } else {
            const int bpa = ((lane ^ (int)pmh) << 2);
#pragma unroll
            for (int cc = 0; cc < 16; cc += 4) {
                v2f XA[2], XAi[2], XB[2], XBi[2];
#pragma unroll
                for (int k = 0; k < 2; ++k) {          // issue DS: cc, cc+1
                    const int t = pidx(cc + k, msbv), t2 = t ^ (int)pmlv;
                    XA[k] = dsx(bpa, rr[t2]); XAi[k] = dsx(bpa, ii[t2]);
                    XB[k] = dsx(bpa, rr[t]);  XBi[k] = dsx(bpa, ii[t]);
                }
#pragma unroll
                for (int k = 2; k < 4; ++k) {          // DPP half: cc+2, cc+3
                    const int t = pidx(cc + k, msbv), t2 = t ^ (int)pmlv;
                    const int c0 = __builtin_parity(t  & (int)smlv);
                    const int c1 = __builtin_parity(t2 & (int)smlv);
                    const v2f DA  = xpartner<pmh>(rr[t2], l16, l32);
                    const v2f DAi = xpartner<pmh>(ii[t2], l16, l32);
                    const v2f DB  = xpartner<pmh>(rr[t],  l16, l32);
                    const v2f DBi = xpartner<pmh>(ii[t],  l16, l32);
                    const v2f A = rr[t], Ai = ii[t], B = rr[t2], Bi = ii[t2];
                    rr[t]  = CRE(c0, A, Ai, DA, DAi);
                    ii[t]  = CIM(c0, A, Ai, DA, DAi);
                    rr[t2] = CRE(c1, B, Bi, DB, DBi);
                    ii[t2] = CIM(c1, B, Bi, DB, DBi);
                }
#pragma unroll
                for (int k = 0; k < 2; ++k) {          // consume DS
                    const int t = pidx(cc + k, msbv), t2 = t ^ (int)pmlv;
                    const int c0 = __builtin_parity(t  & (int)smlv);
                    const int c1 = __builtin_parity(t2 & (int)smlv);
                    const v2f A = rr[t], Ai = ii[t], B = rr[t2], Bi = ii[t2];
                    rr[t]  = CRE(c0, A, Ai, XA[k], XAi[k]);
                    ii[t]  = CIM(c0, A, Ai, XA[k], XAi[k]);
                    rr[t2] = CRE(c1, B, Bi, XB[k], XBi[k]);
                    ii[t2] = CIM(c1, B, Bi, XB[k], XBi[k]);
                }
            }
        }
    }
#undef CSEL
#undef CRE
#undef CIM
}

template <int G>
__device__ __forceinline__ void apply_from(v2f (&rr)[32], v2f (&ii)[32],
                                           const float (*rotm)[8],
                                           int lane, bool l16, bool l32) {
    if constexpr (G < N_GATES) {
        apply_gate<G>(rr, ii, rotm[G], lane, l16, l32);
        apply_from<G + 1>(rr, ii, rotm, lane, l16, l32);
    }
}

__global__ __launch_bounds__(256, 2)
void qsim_kernel(const float* __restrict__ inputs,
                 const float* __restrict__ theta,
                 float* __restrict__ out, int B) {
    __shared__ float rotm[N_GATES][8];
    const int tid  = threadIdx.x;
    const int lane = tid & 63;
    const bool l16 = (lane & 16) != 0;
    const bool l32 = (lane & 32) != 0;
    int b = blockIdx.x * 4 + (tid >> 6);
    if (b >= B) b = B - 1;

    // ---- 48 shared Rot matrices, PennyLane Rot(phi,th,om) ----
    if (tid < N_GATES) {
        const float* th = theta + tid * 3;
        const float phi = th[0], tht = th[1], om = th[2];
        const float ct = __cosf(0.5f * tht), st = __sinf(0.5f * tht);
        const float a = 0.5f * (phi + om), d = 0.5f * (phi - om);
        const float ca = __cosf(a), sa = __sinf(a);
        const float cd = __cosf(d), sd = __sinf(d);
        rotm[tid][0] = ca * ct;  rotm[tid][1] = -sa * ct;   // u00
        rotm[tid][2] = -cd * st; rotm[tid][3] = -sd * st;   // u01
        rotm[tid][4] = cd * st;  rotm[tid][5] = -sd * st;   // u10
        rotm[tid][6] = ca * ct;  rotm[tid][7] = sa * ct;    // u11
    }
    __syncthreads();

    // ---- init: RY-encoded product state (real) ----
    float cw[12], sw[12];
    const float* xin = inputs + b * 12;
#pragma unroll
    for (int w = 0; w < 12; ++w) {
        const float h = 0.5f * xin[w];
        cw[w] = __cosf(h);
        sw[w] = __sinf(h);
    }
    float prodL = 1.0f;
#pragma unroll
    for (int w = 0; w < 6; ++w)
        prodL *= ((lane >> (5 - w)) & 1) ? sw[w] : cw[w];

    // vector index t = j>>1 (j bits 1..5 <-> wires 10..6); h = j&1 <-> wire 11
    float tmp32[32];
    tmp32[0] = prodL;
#pragma unroll
    for (int k = 0; k < 5; ++k) {
        const int n = 1 << k;
#pragma unroll
        for (int idx = 0; idx < n; ++idx) {
            const float v = tmp32[idx];
            tmp32[idx + n] = v * sw[10 - k];
            tmp32[idx]     = v * cw[10 - k];
        }
    }
    v2f rr[32], ii[32];
#pragma unroll
    for (int t = 0; t < 32; ++t) {
        rr[t] = v2f{tmp32[t] * cw[11], tmp32[t] * sw[11]};
        ii[t] = v2f{0.0f, 0.0f};
    }

    // ---- 4 layers x 12 Rot gates (CNOTs folded into masks) ----
    apply_from<0>(rr, ii, rotm, lane, l16, l32);

    // ---- measurement: packed WHT over vector bits + per-q half-combine ----
    v2f pv[32];
#pragma unroll
    for (int t = 0; t < 32; ++t)
        pv[t] = __builtin_elementwise_fma(rr[t], rr[t], ii[t] * ii[t]);
#pragma unroll
    for (int s = 0; s < 5; ++s) {
        const int bit = 1 << s;
#pragma unroll
        for (int t = 0; t < 32; ++t) {
            if (!(t & bit)) {
                const v2f a = pv[t], d = pv[t | bit];
                pv[t]       = a + d;
                pv[t | bit] = a - d;
            }
        }
    }
#pragma unroll
    for (int q = 0; q < 12; ++q) {
        const unsigned mm = CIRC.meas[q];
        const int ml = (int)(mm & 63u), mv = ml >> 1;
        float v = (ml & 1) ? (pv[mv].x - pv[mv].y) : (pv[mv].x + pv[mv].y);
        if (__popc(lane & (int)(mm >> 6)) & 1) v = -v;
        v += __shfl_xor(v, 32, 64);
        v += __shfl_xor(v, 16, 64);
        v += __shfl_xor(v, 8, 64);
        v += __shfl_xor(v, 4, 64);
        v += __shfl_xor(v, 2, 64);
        v += __shfl_xor(v, 1, 64);
        if (lane == 0) out[b * 12 + q] = v;
    }
}

extern "C" void kernel_launch(void* const* d_in, const int* in_sizes, int n_in,
                              void* d_out, int out_size, void* d_ws, size_t ws_size,
                              hipStream_t stream) {
    const float* inputs = (const float*)d_in[0];
    const float* theta  = (const float*)d_in[1];
    float* out = (float*)d_out;
    const int B = in_sizes[0] / 12;
    const int blocks = (B + 3) / 4;
    qsim_kernel<<<blocks, 256, 0, stream>>>(inputs, theta, out, B);
}

// Round 14
// 306.253 us; speedup vs baseline: 1.1507x; 1.1507x over previous
//
#include <hip/hip_runtime.h>

// ---------------------------------------------------------------------------
// 12-qubit state-vector sim, one sample per 64-lane wave, 4 samples/block.
// Storage index p (12 bits): bits 0..5 = per-thread local index j,
// bits 6..11 = lane id. Logical k = M*p over GF(2); CNOTs folded into M at
// compile time; each Rot gate = pair-mask (col of M^-1) + side-mask (row M).
// Wire w <-> bit (11-w) of k (PennyLane big-endian).
//
// Packed layout (R11): rr[t]={re0,re1}, ii[t]={im0,im1}; pure packed FMAs.
// Pipe split (R7/R12): dpp_cost<=2 -> DPP path; else DS (ds_bpermute).
//
// Round-14 change (vs R12; R13's intra-gate DPP hybrid REVERTED — it added
// 4-6-atom DPP work exceeding the stall it covered, 352us):
// SOFTWARE-PIPELINED DS batches: double-buffered issue/consume so group k's
// consume-FMAs cover group k+1's bpermute latency (compiler emits partial
// lgkmcnt waits instead of full drains). Pure reorder, no math change.
// ---------------------------------------------------------------------------

#define N_GATES 48

typedef float v2f __attribute__((ext_vector_type(2)));

#if __has_builtin(__builtin_amdgcn_permlane16_swap) && __has_builtin(__builtin_amdgcn_permlane32_swap)
#define HAS_PLSWAP 1
#else
#define HAS_PLSWAP 0
#endif

struct Circ {
    unsigned pair[N_GATES];
    unsigned side[N_GATES];
    unsigned meas[12];
};

constexpr Circ make_circ() {
    Circ c{};
    unsigned Mrow[12] = {}, Ucol[12] = {};   // M rows, M^-1 columns
    for (int i = 0; i < 12; ++i) { Mrow[i] = 1u << i; Ucol[i] = 1u << i; }
    int g = 0;
    for (int l = 0; l < 4; ++l) {
        for (int w = 0; w < 12; ++w) {
            int b = 11 - w;
            c.pair[g] = Ucol[b];
            c.side[g] = Mrow[b];
            ++g;
        }
        for (int i = 0; i < 11; ++i) {       // CNOT chain (i -> i+1)
            int cb = 11 - i, tb = 10 - i;
            Mrow[tb] ^= Mrow[cb];
            Ucol[cb] ^= Ucol[tb];
        }
        Mrow[11] ^= Mrow[0];                 // CNOT(11 -> 0)
        Ucol[0]  ^= Ucol[11];
    }
    for (int w = 0; w < 12; ++w) c.meas[w] = Mrow[11 - w];
    return c;
}

constexpr Circ CIRC = make_circ();

__device__ __forceinline__ constexpr int pidx(int c, int msb) {
    return ((c & ~(msb - 1)) << 1) | (c & (msb - 1));
}

constexpr int dpp_cost(unsigned pmh) {
    constexpr int low[16] = {0,1,1,1,2,2,2,1,2,3,3,3,2,2,2,1};
    int c = low[pmh & 15u];
    if (pmh & 16u) c += 2;
    if (pmh & 32u) c += 2;
    return c;
}

// ---- VALU-pipe lane-xor primitives --------------------------------------
__device__ __forceinline__ int dpp1(int w){ return __builtin_amdgcn_mov_dpp(w, 0xB1,  0xF, 0xF, true); }
__device__ __forceinline__ int dpp2(int w){ return __builtin_amdgcn_mov_dpp(w, 0x4E,  0xF, 0xF, true); }
__device__ __forceinline__ int dpp3(int w){ return __builtin_amdgcn_mov_dpp(w, 0x1B,  0xF, 0xF, true); }
__device__ __forceinline__ int dpp7(int w){ return __builtin_amdgcn_mov_dpp(w, 0x141, 0xF, 0xF, true); }
__device__ __forceinline__ int dppF(int w){ return __builtin_amdgcn_mov_dpp(w, 0x140, 0xF, 0xF, true); }

template <unsigned V>
__device__ __forceinline__ int dpp_low(int w) {
    if constexpr (V == 0)  return w;
    else if constexpr (V == 1)  return dpp1(w);
    else if constexpr (V == 2)  return dpp2(w);
    else if constexpr (V == 3)  return dpp3(w);
    else if constexpr (V == 7)  return dpp7(w);
    else if constexpr (V == 15) return dppF(w);
    else if constexpr (V == 4)  return dpp3(dpp7(w));
    else if constexpr (V == 5)  return dpp2(dpp7(w));
    else if constexpr (V == 6)  return dpp1(dpp7(w));
    else if constexpr (V == 8)  return dpp7(dppF(w));
    else if constexpr (V == 12) return dpp3(dppF(w));
    else if constexpr (V == 13) return dpp2(dppF(w));
    else if constexpr (V == 14) return dpp1(dppF(w));
    else if constexpr (V == 9)  return dpp1(dpp7(dppF(w)));
    else if constexpr (V == 10) return dpp2(dpp7(dppF(w)));
    else return dpp3(dpp7(dppF(w)));   // V == 11
}

template <unsigned PMH>
__device__ __forceinline__ unsigned xword(unsigned w, bool l16, bool l32) {
    unsigned t = (unsigned)dpp_low<PMH & 15u>((int)w);
#if HAS_PLSWAP
    if constexpr ((PMH & 16u) != 0) {
        auto r = __builtin_amdgcn_permlane16_swap(t, t, false, false);
        t = l16 ? r[0] : r[1];
    }
    if constexpr ((PMH & 32u) != 0) {
        auto r = __builtin_amdgcn_permlane32_swap(t, t, false, false);
        t = l32 ? r[0] : r[1];
    }
#else
    if constexpr ((PMH & 48u) != 0)
        t = (unsigned)__shfl_xor((int)t, (int)(PMH & 48u), 64);
#endif
    return t;
}

template <unsigned PMH>
__device__ __forceinline__ v2f xpartner(v2f v, bool l16, bool l32) {
    union { v2f f; unsigned u[2]; } a;
    a.f = v;
    a.u[0] = xword<PMH>(a.u[0], l16, l32);
    a.u[1] = xword<PMH>(a.u[1], l16, l32);
    return a.f;
}

// DS exchange with hoisted byte address (addr = (lane^pmh)<<2)
__device__ __forceinline__ v2f dsx(int addr, v2f v) {
    union { v2f f; int u[2]; } a;
    a.f = v;
    a.u[0] = __builtin_amdgcn_ds_bpermute(addr, a.u[0]);
    a.u[1] = __builtin_amdgcn_ds_bpermute(addr, a.u[1]);
    return a.f;
}

// out = c1*x1 + c2*x2 + c3*x3 + c4*x4 (packed, no swizzles)
__device__ __forceinline__ v2f fmad4(v2f c1, v2f x1, v2f c2, v2f x2,
                                     v2f c3, v2f x3, v2f c4, v2f x4) {
    return __builtin_elementwise_fma(c1, x1,
           __builtin_elementwise_fma(c2, x2,
           __builtin_elementwise_fma(c3, x3, c4 * x4)));
}

template <int G>
__device__ __forceinline__ void apply_gate(v2f (&rr)[32], v2f (&ii)[32],
                                           const float* __restrict__ m,
                                           int lane, bool l16, bool l32) {
    constexpr unsigned pm  = CIRC.pair[G];
    constexpr unsigned sm  = CIRC.side[G];
    constexpr unsigned pml = pm & 63u,  pmh = pm >> 6;
    constexpr unsigned sml = sm & 63u,  smh = sm >> 6;
    constexpr unsigned smlv = sml >> 1, pmlv = pml >> 1;
    constexpr bool smlodd = (sml & 1u) != 0;
    constexpr bool pmlodd = (pml & 1u) != 0;
    constexpr bool use_dpp = (pmh != 0u) && (dpp_cost(pmh) <= 2);   // R7/R12 calibration

    const float u00r = m[0], u00i = m[1], u01r = m[2], u01i = m[3];
    const float u10r = m[4], u10i = m[5], u11r = m[6], u11i = m[7];
    const int sL = __popc(lane & (int)smh) & 1;
    // coef(s): own P(s)=s?u11:u00, partner Q(s)=s?u10:u01; a: s=sL, b: s=!sL
    const float par = sL ? u11r : u00r, pai = sL ? u11i : u00i;
    const float pbr = sL ? u00r : u11r, pbi = sL ? u00i : u11i;
    const float qar = sL ? u10r : u01r, qai = sL ? u10i : u01i;
    const float qbr = sL ? u01r : u10r, qbi = sL ? u01i : u10i;
    // element j=2t+h: s = sL ^ parity(t&smlv) ^ (h&smlodd).
    v2f PR0, PI0, PN0, QR0, QI0, QN0, PR1, PI1, PN1, QR1, QI1, QN1;
    if constexpr (!smlodd) {
        PR0 = v2f{par, par}; PI0 = v2f{pai, pai}; PN0 = v2f{-pai, -pai};
        QR0 = v2f{qar, qar}; QI0 = v2f{qai, qai}; QN0 = v2f{-qai, -qai};
        PR1 = v2f{pbr, pbr}; PI1 = v2f{pbi, pbi}; PN1 = v2f{-pbi, -pbi};
        QR1 = v2f{qbr, qbr}; QI1 = v2f{qbi, qbi}; QN1 = v2f{-qbi, -qbi};
    } else {
        PR0 = v2f{par, pbr}; PI0 = v2f{pai, pbi}; PN0 = v2f{-pai, -pbi};
        QR0 = v2f{qar, qbr}; QI0 = v2f{qai, qbi}; QN0 = v2f{-qai, -qbi};
        PR1 = v2f{pbr, par}; PI1 = v2f{pbi, pai}; PN1 = v2f{-pbi, -pai};
        QR1 = v2f{qbr, qar}; QI1 = v2f{qbi, qai}; QN1 = v2f{-qbi, -qai};
    }
#define CSEL(c, X) ((c) ? X##1 : X##0)
#define CRE(c, A, Ai, B, Bi) fmad4(CSEL(c,PR), A,  CSEL(c,PN), Ai, CSEL(c,QR), B,  CSEL(c,QN), Bi)
#define CIM(c, A, Ai, B, Bi) fmad4(CSEL(c,PR), Ai, CSEL(c,PI), A,  CSEL(c,QR), Bi, CSEL(c,QI), B)

    if constexpr (pmh == 0u && pml == 1u) {
        // partner inside the v2f: B = A.yx
#pragma unroll
        for (int t = 0; t < 32; ++t) {
            const int c0 = __builtin_parity(t & (int)smlv);
            const v2f A = rr[t], Ai = ii[t];
            const v2f B = A.yx, Bi = Ai.yx;
            rr[t] = CRE(c0, A, Ai, B, Bi);
            ii[t] = CIM(c0, A, Ai, B, Bi);
        }
    } else if constexpr (pmh == 0u && !pmlodd) {
        // in-thread vector pairs (t, t^pmlv), same half
        constexpr int msbv = 1 << (31 - __builtin_clz(pmlv));
#pragma unroll
        for (int c = 0; c < 16; ++c) {
            const int t = pidx(c, msbv), t2 = t ^ (int)pmlv;
            const int c0 = __builtin_parity(t  & (int)smlv);
            const int c1 = __builtin_parity(t2 & (int)smlv);
            const v2f A = rr[t], Ai = ii[t], B = rr[t2], Bi = ii[t2];
            rr[t]  = CRE(c0, A, Ai, B, Bi);
            ii[t]  = CIM(c0, A, Ai, B, Bi);
            rr[t2] = CRE(c1, B, Bi, A, Ai);
            ii[t2] = CIM(c1, B, Bi, A, Ai);
        }
    } else if constexpr (pmh == 0u) {
        // in-thread pairs (t, t^pmlv) with HALF SWAP (pml odd > 1)
        constexpr int msbv = 1 << (31 - __builtin_clz(pmlv));
#pragma unroll
        for (int c = 0; c < 16; ++c) {
            const int t = pidx(c, msbv), t2 = t ^ (int)pmlv;
            const int c0 = __builtin_parity(t  & (int)smlv);
            const int c1 = __builtin_parity(t2 & (int)smlv);
            const v2f A = rr[t], Ai = ii[t], B = rr[t2], Bi = ii[t2];
            const v2f BS = B.yx, BSi = Bi.yx, AS = A.yx, ASi = Ai.yx;
            rr[t]  = CRE(c0, A, Ai, BS, BSi);
            ii[t]  = CIM(c0, A, Ai, BS, BSi);
            rr[t2] = CRE(c1, B, Bi, AS, ASi);
            ii[t2] = CIM(c1, B, Bi, AS, ASi);
        }
    } else if constexpr (pml == 0u) {
        // pure cross-lane: partner = same vector, lane^pmh
        if constexpr (use_dpp) {
#pragma unroll
            for (int t = 0; t < 32; ++t) {
                const int c0 = __builtin_parity(t & (int)smlv);
                const v2f B  = xpartner<pmh>(rr[t], l16, l32);
                const v2f Bi = xpartner<pmh>(ii[t], l16, l32);
                const v2f A = rr[t], Ai = ii[t];
                rr[t] = CRE(c0, A, Ai, B, Bi);
                ii[t] = CIM(c0, A, Ai, B, Bi);
            }
        } else {
            // R14: double-buffered pipeline — issue group k+1, consume group k
            const int bpa = ((lane ^ (int)pmh) << 2);
            v2f Ba[4], Bia[4], Bb[4], Bib[4];
#define ISS(BUF, BIB, T0) \
            _Pragma("unroll") for (int k = 0; k < 4; ++k) { \
                BUF[k] = dsx(bpa, rr[(T0) + k]); \
                BIB[k] = dsx(bpa, ii[(T0) + k]); }
#define CON(BUF, BIB, T0) \
            _Pragma("unroll") for (int k = 0; k < 4; ++k) { \
                const int t = (T0) + k; \
                const int c0 = __builtin_parity(t & (int)smlv); \
                const v2f A = rr[t], Ai = ii[t]; \
                rr[t] = CRE(c0, A, Ai, BUF[k], BIB[k]); \
                ii[t] = CIM(c0, A, Ai, BUF[k], BIB[k]); }
            ISS(Ba, Bia, 0)
            ISS(Bb, Bib, 4)  CON(Ba, Bia, 0)
            ISS(Ba, Bia, 8)  CON(Bb, Bib, 4)
            ISS(Bb, Bib, 12) CON(Ba, Bia, 8)
            ISS(Ba, Bia, 16) CON(Bb, Bib, 12)
            ISS(Bb, Bib, 20) CON(Ba, Bia, 16)
            ISS(Ba, Bia, 24) CON(Bb, Bib, 20)
            ISS(Bb, Bib, 28) CON(Ba, Bia, 24)
            CON(Bb, Bib, 28)
#undef ISS
#undef CON
        }
    } else if constexpr (pmlodd && pmlv == 0u) {
        // partner = (lane^pmh, same t, h^1): exchange + half swap
        if constexpr (use_dpp) {
#pragma unroll
            for (int t = 0; t < 32; ++t) {
                const int c0 = __builtin_parity(t & (int)smlv);
                const v2f X  = xpartner<pmh>(rr[t], l16, l32);
                const v2f Xi = xpartner<pmh>(ii[t], l16, l32);
                const v2f A = rr[t], Ai = ii[t];
                const v2f B = X.yx, Bi = Xi.yx;
                rr[t] = CRE(c0, A, Ai, B, Bi);
                ii[t] = CIM(c0, A, Ai, B, Bi);
            }
        } else {
            const int bpa = ((lane ^ (int)pmh) << 2);
            v2f Xa[4], Xia[4], Xb[4], Xib[4];
#define ISS(BUF, BIB, T0) \
            _Pragma("unroll") for (int k = 0; k < 4; ++k) { \
                BUF[k] = dsx(bpa, rr[(T0) + k]); \
                BIB[k] = dsx(bpa, ii[(T0) + k]); }
#define CONY(BUF, BIB, T0) \
            _Pragma("unroll") for (int k = 0; k < 4; ++k) { \
                const int t = (T0) + k; \
                const int c0 = __builtin_parity(t & (int)smlv); \
                const v2f A = rr[t], Ai = ii[t]; \
                const v2f Bv = BUF[k].yx, Bvi = BIB[k].yx; \
                rr[t] = CRE(c0, A, Ai, Bv, Bvi); \
                ii[t] = CIM(c0, A, Ai, Bv, Bvi); }
            ISS(Xa, Xia, 0)
            ISS(Xb, Xib, 4)  CONY(Xa, Xia, 0)
            ISS(Xa, Xia, 8)  CONY(Xb, Xib, 4)
            ISS(Xb, Xib, 12) CONY(Xa, Xia, 8)
            ISS(Xa, Xia, 16) CONY(Xb, Xib, 12)
            ISS(Xb, Xib, 20) CONY(Xa, Xia, 16)
            ISS(Xa, Xia, 24) CONY(Xb, Xib, 20)
            ISS(Xb, Xib, 28) CONY(Xa, Xia, 24)
            CONY(Xb, Xib, 28)
#undef ISS
#undef CONY
        }
    } else if constexpr (pmlodd) {
        // pairs (t, t^pmlv) with lane exchange + half swap
        constexpr int msbv = 1 << (31 - __builtin_clz(pmlv));
        if constexpr (use_dpp) {
#pragma unroll
            for (int c = 0; c < 16; ++c) {
                const int t = pidx(c, msbv), t2 = t ^ (int)pmlv;
                const int c0 = __builtin_parity(t  & (int)smlv);
                const int c1 = __builtin_parity(t2 & (int)smlv);
                const v2f XA  = xpartner<pmh>(rr[t2], l16, l32);
                const v2f XAi = xpartner<pmh>(ii[t2], l16, l32);
                const v2f XB  = xpartner<pmh>(rr[t],  l16, l32);
                const v2f XBi = xpartner<pmh>(ii[t],  l16, l32);
                const v2f A = rr[t], Ai = ii[t], B = rr[t2], Bi = ii[t2];
                const v2f YA = XA.yx, YAi = XAi.yx, YB = XB.yx, YBi = XBi.yx;
                rr[t]  = CRE(c0, A, Ai, YA, YAi);
                ii[t]  = CIM(c0, A, Ai, YA, YAi);
                rr[t2] = CRE(c1, B, Bi, YB, YBi);
                ii[t2] = CIM(c1, B, Bi, YB, YBi);
            }
        } else {
            const int bpa = ((lane ^ (int)pmh) << 2);
            v2f PAa[2], PAia[2], PBa[2], PBia[2];
            v2f PAb[2], PAib[2], PBb[2], PBib[2];
#define ISSM(PA, PAI, PB, PBI, CC) \
            _Pragma("unroll") for (int k = 0; k < 2; ++k) { \
                const int t = pidx((CC) + k, msbv), t2 = t ^ (int)pmlv; \
                PA[k] = dsx(bpa, rr[t2]); PAI[k] = dsx(bpa, ii[t2]); \
                PB[k] = dsx(bpa, rr[t]);  PBI[k] = dsx(bpa, ii[t]); }
#define CONMY(PA, PAI, PB, PBI, CC) \
            _Pragma("unroll") for (int k = 0; k < 2; ++k) { \
                const int t = pidx((CC) + k, msbv), t2 = t ^ (int)pmlv; \
                const int c0 = __builtin_parity(t  & (int)smlv); \
                const int c1 = __builtin_parity(t2 & (int)smlv); \
                const v2f A = rr[t], Ai = ii[t], B = rr[t2], Bi = ii[t2]; \
                rr[t]  = CRE(c0, A, Ai, PA[k].yx, PAI[k].yx); \
                ii[t]  = CIM(c0, A, Ai, PA[k].yx, PAI[k].yx); \
                rr[t2] = CRE(c1, B, Bi, PB[k].yx, PBI[k].yx); \
                ii[t2] = CIM(c1, B, Bi, PB[k].yx, PBI[k].yx); }
            ISSM(PAa, PAia, PBa, PBia, 0)
            ISSM(PAb, PAib, PBb, PBib, 2)  CONMY(PAa, PAia, PBa, PBia, 0)
            ISSM(PAa, PAia, PBa, PBia, 4)  CONMY(PAb, PAib, PBb, PBib, 2)
            ISSM(PAb, PAib, PBb, PBib, 6)  CONMY(PAa, PAia, PBa, PBia, 4)
            ISSM(PAa, PAia, PBa, PBia, 8)  CONMY(PAb, PAib, PBb, PBib, 6)
            ISSM(PAb, PAib, PBb, PBib, 10) CONMY(PAa, PAia, PBa, PBia, 8)
            ISSM(PAa, PAia, PBa, PBia, 12) CONMY(PAb, PAib, PBb, PBib, 10)
            ISSM(PAb, PAib, PBb, PBib, 14) CONMY(PAa, PAia, PBa, PBia, 12)
            CONMY(PAb, PAib, PBb, PBib, 14)
#undef ISSM
#undef CONMY
        }
    } else {
        // mixed, pml even: pairs (t, t^pmlv) with lane exchange
        constexpr int msbv = 1 << (31 - __builtin_clz(pmlv));
        if constexpr (use_dpp) {
#pragma unroll
            for (int c = 0; c < 16; ++c) {
                const int t = pidx(c, msbv), t2 = t ^ (int)pmlv;
                const int c0 = __builtin_parity(t  & (int)smlv);
                const int c1 = __builtin_parity(t2 & (int)smlv);
                const v2f XA  = xpartner<pmh>(rr[t2], l16, l32);
                const v2f XAi = xpartner<pmh>(ii[t2], l16, l32);
                const v2f XB  = xpartner<pmh>(rr[t],  l16, l32);
                const v2f XBi = xpartner<pmh>(ii[t],  l16, l32);
                const v2f A = rr[t], Ai = ii[t], B = rr[t2], Bi = ii[t2];
                rr[t]  = CRE(c0, A, Ai, XA, XAi);
                ii[t]  = CIM(c0, A, Ai, XA, XAi);
                rr[t2] = CRE(c1, B, Bi, XB, XBi);
                ii[t2] = CIM(c1, B, Bi, XB, XBi);
            }
        } else {
            const int bpa = ((lane ^ (int)pmh) << 2);
            v2f PAa[2], PAia[2], PBa[2], PBia[2];
            v2f PAb[2], PAib[2], PBb[2], PBib[2];
#define ISSM(PA, PAI, PB, PBI, CC) \
            _Pragma("unroll") for (int k = 0; k < 2; ++k) { \
                const int t = pidx((CC) + k, msbv), t2 = t ^ (int)pmlv; \
                PA[k] = dsx(bpa, rr[t2]); PAI[k] = dsx(bpa, ii[t2]); \
                PB[k] = dsx(bpa, rr[t]);  PBI[k] = dsx(bpa, ii[t]); }
#define CONM(PA, PAI, PB, PBI, CC) \
            _Pragma("unroll") for (int k = 0; k < 2; ++k) { \
                const int t = pidx((CC) + k, msbv), t2 = t ^ (int)pmlv; \
                const int c0 = __builtin_parity(t  & (int)smlv); \
                const int c1 = __builtin_parity(t2 & (int)smlv); \
                const v2f A = rr[t], Ai = ii[t], B = rr[t2], Bi = ii[t2]; \
                rr[t]  = CRE(c0, A, Ai, PA[k], PAI[k]); \
                ii[t]  = CIM(c0, A, Ai, PA[k], PAI[k]); \
                rr[t2] = CRE(c1, B, Bi, PB[k], PBI[k]); \
                ii[t2] = CIM(c1, B, Bi, PB[k], PBI[k]); }
            ISSM(PAa, PAia, PBa, PBia, 0)
            ISSM(PAb, PAib, PBb, PBib, 2)  CONM(PAa, PAia, PBa, PBia, 0)
            ISSM(PAa, PAia, PBa, PBia, 4)  CONM(PAb, PAib, PBb, PBib, 2)
            ISSM(PAb, PAib, PBb, PBib, 6)  CONM(PAa, PAia, PBa, PBia, 4)
            ISSM(PAa, PAia, PBa, PBia, 8)  CONM(PAb, PAib, PBb, PBib, 6)
            ISSM(PAb, PAib, PBb, PBib, 10) CONM(PAa, PAia, PBa, PBia, 8)
            ISSM(PAa, PAia, PBa, PBia, 12) CONM(PAb, PAib, PBb, PBib, 10)
            ISSM(PAb, PAib, PBb, PBib, 14) CONM(PAa, PAia, PBa, PBia, 12)
            CONM(PAb, PAib, PBb, PBib, 14)
#undef ISSM
#undef CONM
        }
    }
#undef CSEL
#undef CRE
#undef CIM
}

template <int G>
__device__ __forceinline__ void apply_from(v2f (&rr)[32], v2f (&ii)[32],
                                           const float (*rotm)[8],
                                           int lane, bool l16, bool l32) {
    if constexpr (G < N_GATES) {
        apply_gate<G>(rr, ii, rotm[G], lane, l16, l32);
        apply_from<G + 1>(rr, ii, rotm, lane, l16, l32);
    }
}

__global__ __launch_bounds__(256, 2)
void qsim_kernel(const float* __restrict__ inputs,
                 const float* __restrict__ theta,
                 float* __restrict__ out, int B) {
    __shared__ float rotm[N_GATES][8];
    const int tid  = threadIdx.x;
    const int lane = tid & 63;
    const bool l16 = (lane & 16) != 0;
    const bool l32 = (lane & 32) != 0;
    int b = blockIdx.x * 4 + (tid >> 6);
    if (b >= B) b = B - 1;

    // ---- 48 shared Rot matrices, PennyLane Rot(phi,th,om) ----
    if (tid < N_GATES) {
        const float* th = theta + tid * 3;
        const float phi = th[0], tht = th[1], om = th[2];
        const float ct = __cosf(0.5f * tht), st = __sinf(0.5f * tht);
        const float a = 0.5f * (phi + om), d = 0.5f * (phi - om);
        const float ca = __cosf(a), sa = __sinf(a);
        const float cd = __cosf(d), sd = __sinf(d);
        rotm[tid][0] = ca * ct;  rotm[tid][1] = -sa * ct;   // u00
        rotm[tid][2] = -cd * st; rotm[tid][3] = -sd * st;   // u01
        rotm[tid][4] = cd * st;  rotm[tid][5] = -sd * st;   // u10
        rotm[tid][6] = ca * ct;  rotm[tid][7] = sa * ct;    // u11
    }
    __syncthreads();

    // ---- init: RY-encoded product state (real) ----
    float cw[12], sw[12];
    const float* xin = inputs + b * 12;
#pragma unroll
    for (int w = 0; w < 12; ++w) {
        const float h = 0.5f * xin[w];
        cw[w] = __cosf(h);
        sw[w] = __sinf(h);
    }
    float prodL = 1.0f;
#pragma unroll
    for (int w = 0; w < 6; ++w)
        prodL *= ((lane >> (5 - w)) & 1) ? sw[w] : cw[w];

    // vector index t = j>>1 (j bits 1..5 <-> wires 10..6); h = j&1 <-> wire 11
    float tmp32[32];
    tmp32[0] = prodL;
#pragma unroll
    for (int k = 0; k < 5; ++k) {
        const int n = 1 << k;
#pragma unroll
        for (int idx = 0; idx < n; ++idx) {
            const float v = tmp32[idx];
            tmp32[idx + n] = v * sw[10 - k];
            tmp32[idx]     = v * cw[10 - k];
        }
    }
    v2f rr[32], ii[32];
#pragma unroll
    for (int t = 0; t < 32; ++t) {
        rr[t] = v2f{tmp32[t] * cw[11], tmp32[t] * sw[11]};
        ii[t] = v2f{0.0f, 0.0f};
    }

    // ---- 4 layers x 12 Rot gates (CNOTs folded into masks) ----
    apply_from<0>(rr, ii, rotm, lane, l16, l32);

    // ---- measurement: packed WHT over vector bits + per-q half-combine ----
    v2f pv[32];
#pragma unroll
    for (int t = 0; t < 32; ++t)
        pv[t] = __builtin_elementwise_fma(rr[t], rr[t], ii[t] * ii[t]);
#pragma unroll
    for (int s = 0; s < 5; ++s) {
        const int bit = 1 << s;
#pragma unroll
        for (int t = 0; t < 32; ++t) {
            if (!(t & bit)) {
                const v2f a = pv[t], d = pv[t | bit];
                pv[t]       = a + d;
                pv[t | bit] = a - d;
            }
        }
    }
#pragma unroll
    for (int q = 0; q < 12; ++q) {
        const unsigned mm = CIRC.meas[q];
        const int ml = (int)(mm & 63u), mv = ml >> 1;
        float v = (ml & 1) ? (pv[mv].x - pv[mv].y) : (pv[mv].x + pv[mv].y);
        if (__popc(lane & (int)(mm >> 6)) & 1) v = -v;
        v += __shfl_xor(v, 32, 64);
        v += __shfl_xor(v, 16, 64);
        v += __shfl_xor(v, 8, 64);
        v += __shfl_xor(v, 4, 64);
        v += __shfl_xor(v, 2, 64);
        v += __shfl_xor(v, 1, 64);
        if (lane == 0) out[b * 12 + q] = v;
    }
}

extern "C" void kernel_launch(void* const* d_in, const int* in_sizes, int n_in,
                              void* d_out, int out_size, void* d_ws, size_t ws_size,
                              hipStream_t stream) {
    const float* inputs = (const float*)d_in[0];
    const float* theta  = (const float*)d_in[1];
    float* out = (float*)d_out;
    const int B = in_sizes[0] / 12;
    const int blocks = (B + 3) / 4;
    qsim_kernel<<<blocks, 256, 0, stream>>>(inputs, theta, out, B);
}